// Round 15
// baseline (118.143 us; speedup 1.0000x reference)
//
#include <hip/hip_runtime.h>
#include <hip/hip_fp16.h>

#define N_NODES 100000
#define N_EDGES 1600000
#define D 64
#define ZROW 100000                        // zero sentinel node index

// ---- bucket geometry (fixed-capacity regions) ----
#define NPB   240
#define NB    417
#define CAP   8192

// ---- partition geometry ----
#define EPB   8192
#define PBLK  ((N_EDGES + EPB - 1) / EPB)  // 196
#define CONV2 782                          // ceil(100000/128) conversion blocks

// ---- plane layout: 4 planes x 32B/node (2 uint4), chunk-major ----
#define PSN   100352                       // nodes per plane (padded, > ZROW)
#define PSU   (PSN * 2)                    // uint4 per plane

// ---- ws layout (~40.2 MB; observed ws ~268 MB) ----
#define W3_FFP      0u                            // 4 planes  12.85 MB
#define W3_MEANP    12845056u                     // 4 planes  12.85 MB
#define W3_PACKED   25690112u                     // int[NB*CAP] 13.66 MB
#define W3_GCUR     (W3_PACKED + 4u * NB * CAP)   // 39,354,368
#define W3_NODEOFF  (W3_GCUR + 4u * NB)
#define W3_NODECNT  (W3_NODEOFF + 4u * N_NODES)
#define W3_W16      ((W3_NODECNT + 4u * N_NODES + 15u) & ~15u)  // 16B-aligned
#define W3_NEED     (W3_W16 + 16384u)

typedef __attribute__((ext_vector_type(8))) _Float16 half8;
typedef __attribute__((ext_vector_type(4))) float f32x4;

__device__ inline unsigned int h2bits(__half2 h) { return *(unsigned int*)&h; }
__device__ inline __half2 bits2h(unsigned int u) { return *(__half2*)&u; }
__device__ inline __half2 h2shfl_xor(__half2 x, int mask) {
    int i = *(int*)&x;
    i = __shfl_xor(i, mask);
    return *(__half2*)&i;
}

// ===========================================================================
// 1) Fused partition + conversions.
//    [0,PBLK): counting sort into fixed per-bucket regions.
//    [PBLK,PBLK+CONV2): feat -> f16 PLANES via LDS transpose (128 nodes/blk).
//    Block PBLK+CONV2: W -> f16.
// ===========================================================================
__global__ __launch_bounds__(1024) void k_part_conv(
    const float* __restrict__ feat,
    const int* __restrict__ src, const int* __restrict__ dst,
    const float* __restrict__ Ws, const float* __restrict__ Wn,
    uint4* __restrict__ ffp, unsigned int* __restrict__ w16,
    int* __restrict__ gcur, int* __restrict__ packed)
{
    __shared__ int recs[EPB];        // 32 KB (reused as conv staging)
    __shared__ int cnt[NB];
    __shared__ int scn[512];
    __shared__ int pos[NB];
    __shared__ int cur[NB];
    __shared__ int dlt[NB];

    const int bid = blockIdx.x;
    const int t   = threadIdx.x;

    if (bid >= PBLK) {
        if (bid < PBLK + CONV2) {
            // ---- feat -> plane-major f16, 128 nodes per block ----
            uint4* lds = (uint4*)recs;          // stride 9: 128*9*16 = 18432 B
            const int n0 = (bid - PBLK) * 128;
            {
                const int j  = t >> 3;          // node 0..127
                const int c8 = t & 7;           // 16B chunk 0..7
                const int n  = n0 + j;
                uint4 u = make_uint4(0u, 0u, 0u, 0u);
                if (n < N_NODES) {
                    const float4 x = *(const float4*)(feat + (size_t)n * 64 + c8 * 8);
                    const float4 y = *(const float4*)(feat + (size_t)n * 64 + c8 * 8 + 4);
                    u.x = h2bits(__floats2half2_rn(x.x, x.y));
                    u.y = h2bits(__floats2half2_rn(x.z, x.w));
                    u.z = h2bits(__floats2half2_rn(y.x, y.y));
                    u.w = h2bits(__floats2half2_rn(y.z, y.w));
                }
                lds[j * 9 + c8] = u;
            }
            __syncthreads();
            {
                const int p    = t >> 8;        // plane 0..3
                const int rem  = t & 255;
                const int jj   = rem >> 1;      // node 0..127
                const int half = rem & 1;       // uint4 within 32B
                const int n    = n0 + jj;
                ffp[(size_t)p * PSU + n * 2 + half] = lds[jj * 9 + (p * 2 + half)];
            }
        } else {
            for (int i = t; i < 2048; i += 1024) {
                w16[i]        = h2bits(__floats2half2_rn(Ws[2 * i], Ws[2 * i + 1]));
                w16[2048 + i] = h2bits(__floats2half2_rn(Wn[2 * i], Wn[2 * i + 1]));
            }
        }
        return;
    }

    const int e0 = bid * EPB;
    const int nE = min(EPB, N_EDGES - e0);

    for (int i = t; i < NB; i += 1024) cnt[i] = 0;
    __syncthreads();

    int pk[8], bk[8];
    #pragma unroll
    for (int k = 0; k < 8; ++k) {
        const int i = t + k * 1024;
        if (i < nE) {
            const int d  = dst[e0 + i];
            const int b  = d / NPB;
            const int dl = d - b * NPB;
            pk[k] = src[e0 + i] | (dl << 17);
            bk[k] = b;
            atomicAdd(&cnt[b], 1);
        } else {
            bk[k] = -1;
        }
    }
    __syncthreads();

    if (t < 512) scn[t] = (t < NB) ? cnt[t] : 0;
    __syncthreads();
    for (int o = 1; o < 512; o <<= 1) {
        int x = 0;
        if (t < 512 && t >= o) x = scn[t - o];
        __syncthreads();
        if (t < 512) scn[t] += x;
        __syncthreads();
    }
    if (t < NB) {
        const int v    = cnt[t];
        const int excl = scn[t] - v;
        pos[t] = excl;
        cur[t] = excl;
        dlt[t] = atomicAdd(&gcur[t], v);
    }
    __syncthreads();

    #pragma unroll
    for (int k = 0; k < 8; ++k) {
        if (bk[k] >= 0) {
            const int p = atomicAdd(&cur[bk[k]], 1);
            recs[p] = pk[k];
        }
    }
    __syncthreads();

    const int w    = t >> 6;
    const int lane = t & 63;
    for (int b = w; b < NB; b += 16) {
        const int n = cnt[b];
        const int o = pos[b];
        const int g = b * CAP + dlt[b];
        for (int i = lane; i < n; i += 64)
            packed[g + i] = recs[o + i];
    }
}

// ===========================================================================
// 2) Per-bucket CSR sort (in place, base = bucket*CAP)
// ===========================================================================
__global__ __launch_bounds__(512) void k_sortb(
    const int* __restrict__ gcur,
    int* packed,
    int* __restrict__ node_off, int* __restrict__ node_cnt)
{
    __shared__ int recs[CAP];        // 32 KB
    __shared__ int lcnt[256];
    __shared__ int sc[256];
    __shared__ int lcur[NPB];

    const int t      = threadIdx.x;
    const int bucket = blockIdx.x;
    const int base   = bucket * CAP;
    int total = gcur[bucket];
    if (total > CAP) total = CAP;

    if (t < 256) lcnt[t] = 0;
    __syncthreads();

    for (int i = t; i < total; i += 512) {
        const int r = packed[base + i];
        recs[i] = r;
        atomicAdd(&lcnt[r >> 17], 1);
    }
    __syncthreads();

    if (t < 256) sc[t] = lcnt[t];
    __syncthreads();
    for (int o = 1; o < 256; o <<= 1) {
        int x = 0;
        if (t < 256 && t >= o) x = sc[t - o];
        __syncthreads();
        if (t < 256) sc[t] += x;
        __syncthreads();
    }

    if (t < NPB) {
        const int excl = sc[t] - lcnt[t];
        lcur[t] = excl;
        const int n = bucket * NPB + t;
        if (n < N_NODES) {
            node_off[n] = base + excl;
            node_cnt[n] = lcnt[t];
        }
    }
    __syncthreads();

    for (int i = t; i < total; i += 512) {
        const int r   = recs[i];
        const int pos = atomicAdd(&lcur[r >> 17], 1);
        packed[base + pos] = r & 0x1FFFF;
    }
}

// ===========================================================================
// 3) Plane-sliced aggregation.  Block = 256 thr = 4 waves; plane c = bid&3
//    (XCD-affine: per-XCD gather working set = one 3.2MB plane -> L2-hit).
//    Wave: 2 nodes x (16 edge-slots x 2 lanes/edge, 32B contiguous gather).
//    4-level shfl_xor reduce; means to chunk-major meanp (no false sharing).
// ===========================================================================
__global__ __launch_bounds__(256) void k_agg_plane(
    const uint4* __restrict__ ffp,
    const int* __restrict__ node_off,
    const int* __restrict__ node_cnt,
    const int* __restrict__ packed,
    uint4* __restrict__ meanp)
{
    const int bid  = blockIdx.x;
    const int c    = bid & 3;                 // plane
    const int nb   = (bid >> 2) * 8;          // block's first node
    const int t    = threadIdx.x;
    const int wv   = t >> 6;
    const int lane = t & 63;
    const int half = lane & 1;                // uint4 within the 32B slice
    const int el   = (lane & 31) >> 1;        // edge slot 0..15
    const int n    = nb + wv * 2 + (lane >> 5);

    const int start = node_off[n];
    const int deg   = node_cnt[n];
    const uint4* plane = ffp + (size_t)c * PSU;

    __half2 a0 = __floats2half2_rn(0.f, 0.f);
    __half2 a1 = a0, a2 = a0, a3 = a0;

    for (int e = el; __any(e < deg); e += 16) {
        const int p = (e < deg) ? packed[start + e] : ZROW;
        const uint4 v = plane[p * 2 + half];
        a0 += bits2h(v.x);
        a1 += bits2h(v.y);
        a2 += bits2h(v.z);
        a3 += bits2h(v.w);
    }

    #pragma unroll
    for (int mask = 2; mask <= 16; mask <<= 1) {
        a0 += h2shfl_xor(a0, mask);
        a1 += h2shfl_xor(a1, mask);
        a2 += h2shfl_xor(a2, mask);
        a3 += h2shfl_xor(a3, mask);
    }

    if (el == 0) {
        const float inv = 1.0f / (float)max(deg, 1);
        uint4 mb;
        mb.x = h2bits(__floats2half2_rn(__low2float(a0) * inv, __high2float(a0) * inv));
        mb.y = h2bits(__floats2half2_rn(__low2float(a1) * inv, __high2float(a1) * inv));
        mb.z = h2bits(__floats2half2_rn(__low2float(a2) * inv, __high2float(a2) * inv));
        mb.w = h2bits(__floats2half2_rn(__low2float(a3) * inv, __high2float(a3) * inv));
        meanp[(size_t)c * PSU + n * 2 + half] = mb;
    }
}

// ===========================================================================
// 4) MFMA f16 dense update (4 waves x 16-node tile); A-operands read from
//    the chunk-major planes (chunk k8 -> plane k8>>1, uint4 k8&1).
//    A: row=lane&15, k=(lane>>4)*8+j;  C/D: col=lane&15, row=(lane>>4)*4+r.
// ===========================================================================
__global__ __launch_bounds__(256) void k_update_mfma(
    const uint4* __restrict__ ffp,
    const uint4* __restrict__ meanp,
    const _Float16* __restrict__ w16,     // [2][64][64]: Ws then Wn, K-major
    float* __restrict__ out)
{
    const int wv   = threadIdx.x >> 6;
    const int lane = threadIdx.x & 63;
    const int n0   = blockIdx.x * 64 + wv * 16;
    const int r16  = lane & 15;
    const int g    = lane >> 4;

    half8 bws[4][2], bwn[4][2];
    #pragma unroll
    for (int nt = 0; nt < 4; ++nt) {
        const int cc = nt * 16 + r16;
        #pragma unroll
        for (int kt = 0; kt < 2; ++kt) {
            const int k0 = kt * 32 + g * 8;
            bws[nt][kt] = *(const half8*)(w16 + cc * 64 + k0);
            bwn[nt][kt] = *(const half8*)(w16 + 4096 + cc * 64 + k0);
        }
    }

    const int arow = n0 + r16;
    const int rc   = (arow < N_NODES) ? arow : (N_NODES - 1);

    f32x4 acc[4] = {{0.f,0.f,0.f,0.f}, {0.f,0.f,0.f,0.f},
                    {0.f,0.f,0.f,0.f}, {0.f,0.f,0.f,0.f}};

    #pragma unroll
    for (int kt = 0; kt < 2; ++kt) {
        const int k8 = kt * 4 + g;
        const size_t idx = (size_t)(k8 >> 1) * PSU + (size_t)rc * 2 + (k8 & 1);
        const uint4 af_u = ffp[idx];
        const uint4 am_u = meanp[idx];
        const half8 af = *(const half8*)&af_u;
        const half8 am = *(const half8*)&am_u;
        #pragma unroll
        for (int nt = 0; nt < 4; ++nt) {
            acc[nt] = __builtin_amdgcn_mfma_f32_16x16x32_f16(af, bws[nt][kt], acc[nt], 0, 0, 0);
            acc[nt] = __builtin_amdgcn_mfma_f32_16x16x32_f16(am, bwn[nt][kt], acc[nt], 0, 0, 0);
        }
    }

    #pragma unroll
    for (int nt = 0; nt < 4; ++nt) {
        #pragma unroll
        for (int r = 0; r < 4; ++r) {
            const int ro = n0 + g * 4 + r;
            if (ro < N_NODES)
                out[(size_t)ro * 64 + nt * 16 + r16] = acc[nt][r];
        }
    }
}

// ===========================================================================
// tier-0 fallback (tiny ws): atomic scatter + readlane update
// ===========================================================================
__global__ __launch_bounds__(256) void sage_scatter(
    const float* __restrict__ feat,
    const int*   __restrict__ src,
    const int*   __restrict__ dst,
    float*       __restrict__ agg,
    float*       __restrict__ deg)
{
    const int gtid = blockIdx.x * blockDim.x + threadIdx.x;
    const int edge = gtid >> 6;
    const int lane = gtid & 63;
    if (edge >= N_EDGES) return;
    const int s = src[edge];
    const int d = dst[edge];
    atomicAdd(&agg[d * D + lane], feat[s * D + lane]);
    if (lane == 0) atomicAdd(&deg[d], 1.0f);
}

#define RL(v, l) __int_as_float(__builtin_amdgcn_readlane(__float_as_int(v), (l)))

__global__ __launch_bounds__(256) void k_update_div(
    const float* __restrict__ feat,
    const float* __restrict__ Ws,
    const float* __restrict__ Wn,
    const float* __restrict__ deg,
    float* out)
{
    const int wid   = (blockIdx.x * 256 + threadIdx.x) >> 6;
    const int lane  = threadIdx.x & 63;
    const int nwave = (gridDim.x * 256) >> 6;

    const float4* Ws4 = (const float4*)Ws;
    const float4* Wn4 = (const float4*)Wn;
    float4 ws[16], wn[16];
    #pragma unroll
    for (int j = 0; j < 16; ++j) {
        ws[j] = Ws4[lane * 16 + j];
        wn[j] = Wn4[lane * 16 + j];
    }

    for (int n = wid; n < N_NODES; n += nwave) {
        const float f = feat[n * D + lane];
        const float a = out[n * D + lane] / fmaxf(deg[n], 1.0f);
        float s0 = 0.f, s1 = 0.f, m0 = 0.f, m1 = 0.f;
        #pragma unroll
        for (int j = 0; j < 16; ++j) {
            const float4 w_s = ws[j];
            const float4 w_n = wn[j];
            s0 = fmaf(RL(f, 4 * j + 0), w_s.x, s0);
            s1 = fmaf(RL(f, 4 * j + 1), w_s.y, s1);
            s0 = fmaf(RL(f, 4 * j + 2), w_s.z, s0);
            s1 = fmaf(RL(f, 4 * j + 3), w_s.w, s1);
            m0 = fmaf(RL(a, 4 * j + 0), w_n.x, m0);
            m1 = fmaf(RL(a, 4 * j + 1), w_n.y, m1);
            m0 = fmaf(RL(a, 4 * j + 2), w_n.z, m0);
            m1 = fmaf(RL(a, 4 * j + 3), w_n.w, m1);
        }
        out[n * D + lane] = (s0 + s1) + (m0 + m1);
    }
}

extern "C" void kernel_launch(void* const* d_in, const int* in_sizes, int n_in,
                              void* d_out, int out_size, void* d_ws, size_t ws_size,
                              hipStream_t stream) {
    const float* feat = (const float*)d_in[0];
    const int*   src  = (const int*)d_in[1];
    const int*   dst  = (const int*)d_in[2];
    const float* Ws   = (const float*)d_in[3];
    const float* Wn   = (const float*)d_in[4];
    float* out = (float*)d_out;
    char*  ws  = (char*)d_ws;

    if (ws_size >= W3_NEED) {
        uint4* ffp   = (uint4*)(ws + W3_FFP);
        uint4* meanp = (uint4*)(ws + W3_MEANP);
        int* packed  = (int*)(ws + W3_PACKED);
        int* gcur    = (int*)(ws + W3_GCUR);
        int* noff    = (int*)(ws + W3_NODEOFF);
        int* ncnt    = (int*)(ws + W3_NODECNT);
        unsigned int* w16u = (unsigned int*)(ws + W3_W16);

        hipMemsetAsync(gcur, 0, (size_t)NB * sizeof(int), stream);

        k_part_conv  <<<PBLK + CONV2 + 1, 1024, 0, stream>>>(
            feat, src, dst, Ws, Wn, ffp, w16u, gcur, packed);
        k_sortb      <<<NB, 512, 0, stream>>>(gcur, packed, noff, ncnt);
        k_agg_plane  <<<(N_NODES / 8) * 4, 256, 0, stream>>>(
            ffp, noff, ncnt, packed, meanp);
        k_update_mfma<<<(N_NODES + 63) / 64, 256, 0, stream>>>(
            ffp, meanp, (const _Float16*)w16u, out);
    } else {
        float* deg = (float*)ws;
        hipMemsetAsync(out, 0, (size_t)N_NODES * D * sizeof(float), stream);
        hipMemsetAsync(deg, 0, (size_t)N_NODES * sizeof(float), stream);
        sage_scatter<<<(N_EDGES * 64) / 256, 256, 0, stream>>>(feat, src, dst, out, deg);
        k_update_div<<<1024, 256, 0, stream>>>(feat, Ws, Wn, deg, out);
    }
}

// Round 16
// 94.226 us; speedup vs baseline: 1.2538x; 1.2538x over previous
//
#include <hip/hip_runtime.h>
#include <hip/hip_fp16.h>

#define N_NODES 100000
#define N_EDGES 1600000
#define D 64
#define ZROW 100000                        // zero sentinel node index in ff16

// ---- bucket geometry (fixed-capacity regions) ----
#define NPB   240
#define NB    417
#define CAP   8192

// ---- partition geometry ----
#define EPB   8192
#define PBLK  ((N_EDGES + EPB - 1) / EPB)  // 196

// ---- sortb+conv launch ----
#define CONVB 782                          // feat-conversion blocks (512 thr)

// ---- agg geometry: full-residency persistent waves ----
#define AGG_BLOCKS 2048
#define NWAVES (AGG_BLOCKS * 4)            // 8192 waves

// ---- ws layout (~27.3 MB; observed ws ~268 MB) ----
#define W3_FF16     0u                            // f16[(N_NODES+1)*D] 12.80 MB
#define W3_PACKED   12800128u                     // int[NB*CAP] 13.66 MB
#define W3_GCUR     (W3_PACKED + 4u * NB * CAP)
#define W3_NODEOFF  (W3_GCUR + 4u * NB)
#define W3_NODECNT  (W3_NODEOFF + 4u * N_NODES)
#define W3_W16      (W3_NODECNT + 4u * N_NODES)   // f16[2*64*64] = 16 KB
#define W3_NEED     (W3_W16 + 16384u)

typedef __attribute__((ext_vector_type(8))) _Float16 half8;
typedef __attribute__((ext_vector_type(4))) float f32x4;

__device__ inline unsigned int h2bits(__half2 h) { return *(unsigned int*)&h; }
__device__ inline __half2 bits2h(unsigned int u) { return *(__half2*)&u; }
__device__ inline __half2 h2shfl_xor(__half2 x, int mask) {
    int i = *(int*)&x;
    i = __shfl_xor(i, mask);
    return *(__half2*)&i;
}

// ===========================================================================
// 1) Block-chunked partition into fixed per-bucket regions (R13/R14 core).
// ===========================================================================
__global__ __launch_bounds__(1024) void k_partition(
    const int* __restrict__ src, const int* __restrict__ dst,
    int* __restrict__ gcur, int* __restrict__ packed)
{
    __shared__ int recs[EPB];        // 32 KB
    __shared__ int cnt[NB];
    __shared__ int scn[512];
    __shared__ int pos[NB];
    __shared__ int cur[NB];
    __shared__ int dlt[NB];

    const int bid = blockIdx.x;
    const int t   = threadIdx.x;
    const int e0  = bid * EPB;
    const int nE  = min(EPB, N_EDGES - e0);

    for (int i = t; i < NB; i += 1024) cnt[i] = 0;
    __syncthreads();

    int pk[8], bk[8];
    #pragma unroll
    for (int k = 0; k < 8; ++k) {
        const int i = t + k * 1024;
        if (i < nE) {
            const int d  = dst[e0 + i];
            const int b  = d / NPB;
            const int dl = d - b * NPB;
            pk[k] = src[e0 + i] | (dl << 17);
            bk[k] = b;
            atomicAdd(&cnt[b], 1);
        } else {
            bk[k] = -1;
        }
    }
    __syncthreads();

    if (t < 512) scn[t] = (t < NB) ? cnt[t] : 0;
    __syncthreads();
    for (int o = 1; o < 512; o <<= 1) {
        int x = 0;
        if (t < 512 && t >= o) x = scn[t - o];
        __syncthreads();
        if (t < 512) scn[t] += x;
        __syncthreads();
    }
    if (t < NB) {
        const int v    = cnt[t];
        const int excl = scn[t] - v;
        pos[t] = excl;
        cur[t] = excl;
        dlt[t] = atomicAdd(&gcur[t], v);
    }
    __syncthreads();

    #pragma unroll
    for (int k = 0; k < 8; ++k) {
        if (bk[k] >= 0) {
            const int p = atomicAdd(&cur[bk[k]], 1);
            recs[p] = pk[k];
        }
    }
    __syncthreads();

    const int w    = t >> 6;
    const int lane = t & 63;
    for (int b = w; b < NB; b += 16) {
        const int n = cnt[b];
        const int o = pos[b];
        const int g = b * CAP + dlt[b];
        for (int i = lane; i < n; i += 64)
            packed[g + i] = recs[o + i];
    }
}

// ===========================================================================
// 2) Fused sortb + conversions.  [0,NB): per-bucket CSR sort (512 thr).
//    [NB,NB+CONVB): feat->f16 (independent of partition, rides idle CUs).
//    Block NB+CONVB: W->f16 + zero sentinel row.
// ===========================================================================
__global__ __launch_bounds__(512) void k_sortb_conv(
    const float* __restrict__ feat,
    const float* __restrict__ Ws, const float* __restrict__ Wn,
    unsigned int* __restrict__ ff16, unsigned int* __restrict__ w16,
    const int* __restrict__ gcur,
    int* packed,
    int* __restrict__ node_off, int* __restrict__ node_cnt)
{
    __shared__ int recs[CAP];        // 32 KB
    __shared__ int lcnt[256];
    __shared__ int sc[256];
    __shared__ int lcur[NPB];

    const int bid = blockIdx.x;
    const int t   = threadIdx.x;

    if (bid >= NB) {
        if (bid < NB + CONVB) {
            // feat fp32 -> f16, 800000 uint4 outputs, grid-stride
            const int total = N_NODES * D / 8;
            for (int i = (bid - NB) * 512 + t; i < total; i += CONVB * 512) {
                const float4 x = ((const float4*)feat)[i * 2];
                const float4 y = ((const float4*)feat)[i * 2 + 1];
                uint4 o;
                o.x = h2bits(__floats2half2_rn(x.x, x.y));
                o.y = h2bits(__floats2half2_rn(x.z, x.w));
                o.z = h2bits(__floats2half2_rn(y.x, y.y));
                o.w = h2bits(__floats2half2_rn(y.z, y.w));
                ((uint4*)ff16)[i] = o;
            }
        } else {
            for (int i = t; i < 2048; i += 512) {
                w16[i]        = h2bits(__floats2half2_rn(Ws[2 * i], Ws[2 * i + 1]));
                w16[2048 + i] = h2bits(__floats2half2_rn(Wn[2 * i], Wn[2 * i + 1]));
            }
            if (t < 32) ff16[ZROW * 32 + t] = 0;    // zero sentinel row
        }
        return;
    }

    const int bucket = bid;
    const int base   = bucket * CAP;
    int total = gcur[bucket];
    if (total > CAP) total = CAP;

    if (t < 256) lcnt[t] = 0;
    __syncthreads();

    for (int i = t; i < total; i += 512) {
        const int r = packed[base + i];
        recs[i] = r;
        atomicAdd(&lcnt[r >> 17], 1);
    }
    __syncthreads();

    if (t < 256) sc[t] = lcnt[t];
    __syncthreads();
    for (int o = 1; o < 256; o <<= 1) {
        int x = 0;
        if (t < 256 && t >= o) x = sc[t - o];
        __syncthreads();
        if (t < 256) sc[t] += x;
        __syncthreads();
    }

    if (t < NPB) {
        const int excl = sc[t] - lcnt[t];
        lcur[t] = excl;
        const int n = bucket * NPB + t;
        if (n < N_NODES) {
            node_off[n] = base + excl;
            node_cnt[n] = lcnt[t];
        }
    }
    __syncthreads();

    for (int i = t; i < total; i += 512) {
        const int r   = recs[i];
        const int pos = atomicAdd(&lcur[r >> 17], 1);
        packed[base + pos] = r & 0x1FFFF;
    }
}

// ===========================================================================
// 3) F16 pull aggregation — PERSISTENT, software-pipelined.
//    8192 waves (full residency), ~12 nodes/wave.  While gathering node i,
//    the next node's noff/ncnt/packed loads are already in flight.
//    Inner chunk body identical to R14.  Mean-f16 -> first 128B of out row.
// ===========================================================================
__device__ inline void agg_chunk(
    __half2& a0, __half2& a1, __half2& a2, __half2& a3,
    int p, int m, int sub, int chunk, const unsigned int* __restrict__ ff16)
{
    const int npair = (m + 15) >> 4;
    for (int q = 0; q < npair; ++q) {
        const int e0 = q * 16 + sub;
        const int s0 = __shfl(p, e0)     & 0x1FFFF;
        const int s1 = __shfl(p, e0 + 8) & 0x1FFFF;
        const uint4 v0 = ((const uint4*)ff16)[(size_t)s0 * 8 + chunk];
        const uint4 v1 = ((const uint4*)ff16)[(size_t)s1 * 8 + chunk];
        a0 += bits2h(v0.x);
        a1 += bits2h(v0.y);
        a2 += bits2h(v0.z);
        a3 += bits2h(v0.w);
        a0 += bits2h(v1.x);
        a1 += bits2h(v1.y);
        a2 += bits2h(v1.z);
        a3 += bits2h(v1.w);
    }
}

__global__ __launch_bounds__(256) void k_agg_f16(
    const unsigned int* __restrict__ ff16,
    const int* __restrict__ node_off,
    const int* __restrict__ node_cnt,
    const int* __restrict__ packed,
    float* __restrict__ out)
{
    const int wid   = blockIdx.x * 4 + (threadIdx.x >> 6);
    const int lane  = threadIdx.x & 63;
    const int sub   = lane >> 3;       // edge slot (0..7)
    const int chunk = lane & 7;        // 16B chunk of the 128B row

    int n     = wid;                   // wid < 8192 <= N_NODES always
    int start = node_off[n];
    int deg   = node_cnt[n];
    int p     = (lane < min(deg, 64)) ? packed[start + lane] : ZROW;

    while (true) {
        // ---- prefetch next node's state (hides under current gathers) ----
        const int n1 = n + NWAVES;
        int start1 = 0, deg1 = 0, p1 = ZROW;
        if (n1 < N_NODES) {
            start1 = node_off[n1];
            deg1   = node_cnt[n1];
            if (lane < min(deg1, 64)) p1 = packed[start1 + lane];
        }

        // ---- aggregate current node ----
        __half2 a0 = __floats2half2_rn(0.f, 0.f);
        __half2 a1 = a0, a2 = a0, a3 = a0;

        agg_chunk(a0, a1, a2, a3, p, min(deg, 64), sub, chunk, ff16);
        for (int b = 64; b < deg; b += 64) {           // rare (deg > 64)
            const int rem = min(deg - b, 64);
            const int pp  = (lane < rem) ? packed[start + b + lane] : ZROW;
            agg_chunk(a0, a1, a2, a3, pp, rem, sub, chunk, ff16);
        }

        #pragma unroll
        for (int mask = 8; mask <= 32; mask <<= 1) {
            a0 += h2shfl_xor(a0, mask);
            a1 += h2shfl_xor(a1, mask);
            a2 += h2shfl_xor(a2, mask);
            a3 += h2shfl_xor(a3, mask);
        }

        if (lane < 8) {
            const float inv = 1.0f / (float)((deg > 0) ? deg : 1);
            uint4 mb;
            mb.x = h2bits(__floats2half2_rn(__low2float(a0) * inv, __high2float(a0) * inv));
            mb.y = h2bits(__floats2half2_rn(__low2float(a1) * inv, __high2float(a1) * inv));
            mb.z = h2bits(__floats2half2_rn(__low2float(a2) * inv, __high2float(a2) * inv));
            mb.w = h2bits(__floats2half2_rn(__low2float(a3) * inv, __high2float(a3) * inv));
            ((uint4*)out)[(size_t)n * 16 + lane] = mb;   // mean-f16, row head
        }

        if (n1 >= N_NODES) break;
        n = n1; start = start1; deg = deg1; p = p1;
    }
}

// ===========================================================================
// 4) MFMA f16 dense update (R14: 256 thr = 4 waves x 16-node tile).
//    A: row=lane&15, k=(lane>>4)*8+j;  C/D: col=lane&15, row=(lane>>4)*4+r.
// ===========================================================================
__global__ __launch_bounds__(256) void k_update_mfma(
    const unsigned int* __restrict__ ff16,
    const _Float16* __restrict__ w16,     // [2][64][64]: Ws then Wn, K-major
    float* out)
{
    const int wv   = threadIdx.x >> 6;
    const int lane = threadIdx.x & 63;
    const int n0   = blockIdx.x * 64 + wv * 16;
    const int r16  = lane & 15;
    const int g    = lane >> 4;

    half8 bws[4][2], bwn[4][2];
    #pragma unroll
    for (int nt = 0; nt < 4; ++nt) {
        const int c = nt * 16 + r16;
        #pragma unroll
        for (int kt = 0; kt < 2; ++kt) {
            const int k0 = kt * 32 + g * 8;
            bws[nt][kt] = *(const half8*)(w16 + c * 64 + k0);
            bwn[nt][kt] = *(const half8*)(w16 + 4096 + c * 64 + k0);
        }
    }

    const int arow = n0 + r16;
    const int rc   = (arow < N_NODES) ? arow : (N_NODES - 1);

    f32x4 acc[4] = {{0.f,0.f,0.f,0.f}, {0.f,0.f,0.f,0.f},
                    {0.f,0.f,0.f,0.f}, {0.f,0.f,0.f,0.f}};

    #pragma unroll
    for (int kt = 0; kt < 2; ++kt) {
        const int k8 = kt * 4 + g;
        const uint4 af_u = ((const uint4*)ff16)[(size_t)rc * 8 + k8];
        const uint4 am_u = ((const uint4*)out )[(size_t)rc * 16 + k8];
        const half8 af = *(const half8*)&af_u;
        const half8 am = *(const half8*)&am_u;
        #pragma unroll
        for (int nt = 0; nt < 4; ++nt) {
            acc[nt] = __builtin_amdgcn_mfma_f32_16x16x32_f16(af, bws[nt][kt], acc[nt], 0, 0, 0);
            acc[nt] = __builtin_amdgcn_mfma_f32_16x16x32_f16(am, bwn[nt][kt], acc[nt], 0, 0, 0);
        }
    }

    #pragma unroll
    for (int nt = 0; nt < 4; ++nt) {
        #pragma unroll
        for (int r = 0; r < 4; ++r) {
            const int ro = n0 + g * 4 + r;
            if (ro < N_NODES)
                out[(size_t)ro * 64 + nt * 16 + r16] = acc[nt][r];
        }
    }
}

// ===========================================================================
// tier-0 fallback (tiny ws): atomic scatter + readlane update
// ===========================================================================
__global__ __launch_bounds__(256) void sage_scatter(
    const float* __restrict__ feat,
    const int*   __restrict__ src,
    const int*   __restrict__ dst,
    float*       __restrict__ agg,
    float*       __restrict__ deg)
{
    const int gtid = blockIdx.x * blockDim.x + threadIdx.x;
    const int edge = gtid >> 6;
    const int lane = gtid & 63;
    if (edge >= N_EDGES) return;
    const int s = src[edge];
    const int d = dst[edge];
    atomicAdd(&agg[d * D + lane], feat[s * D + lane]);
    if (lane == 0) atomicAdd(&deg[d], 1.0f);
}

#define RL(v, l) __int_as_float(__builtin_amdgcn_readlane(__float_as_int(v), (l)))

__global__ __launch_bounds__(256) void k_update_div(
    const float* __restrict__ feat,
    const float* __restrict__ Ws,
    const float* __restrict__ Wn,
    const float* __restrict__ deg,
    float* out)
{
    const int wid   = (blockIdx.x * 256 + threadIdx.x) >> 6;
    const int lane  = threadIdx.x & 63;
    const int nwave = (gridDim.x * 256) >> 6;

    const float4* Ws4 = (const float4*)Ws;
    const float4* Wn4 = (const float4*)Wn;
    float4 ws[16], wn[16];
    #pragma unroll
    for (int j = 0; j < 16; ++j) {
        ws[j] = Ws4[lane * 16 + j];
        wn[j] = Wn4[lane * 16 + j];
    }

    for (int n = wid; n < N_NODES; n += nwave) {
        const float f = feat[n * D + lane];
        const float a = out[n * D + lane] / fmaxf(deg[n], 1.0f);
        float s0 = 0.f, s1 = 0.f, m0 = 0.f, m1 = 0.f;
        #pragma unroll
        for (int j = 0; j < 16; ++j) {
            const float4 w_s = ws[j];
            const float4 w_n = wn[j];
            s0 = fmaf(RL(f, 4 * j + 0), w_s.x, s0);
            s1 = fmaf(RL(f, 4 * j + 1), w_s.y, s1);
            s0 = fmaf(RL(f, 4 * j + 2), w_s.z, s0);
            s1 = fmaf(RL(f, 4 * j + 3), w_s.w, s1);
            m0 = fmaf(RL(a, 4 * j + 0), w_n.x, m0);
            m1 = fmaf(RL(a, 4 * j + 1), w_n.y, m1);
            m0 = fmaf(RL(a, 4 * j + 2), w_n.z, m0);
            m1 = fmaf(RL(a, 4 * j + 3), w_n.w, m1);
        }
        out[n * D + lane] = (s0 + s1) + (m0 + m1);
    }
}

extern "C" void kernel_launch(void* const* d_in, const int* in_sizes, int n_in,
                              void* d_out, int out_size, void* d_ws, size_t ws_size,
                              hipStream_t stream) {
    const float* feat = (const float*)d_in[0];
    const int*   src  = (const int*)d_in[1];
    const int*   dst  = (const int*)d_in[2];
    const float* Ws   = (const float*)d_in[3];
    const float* Wn   = (const float*)d_in[4];
    float* out = (float*)d_out;
    char*  ws  = (char*)d_ws;

    if (ws_size >= W3_NEED) {
        unsigned int* ff16 = (unsigned int*)(ws + W3_FF16);
        int* packed = (int*)(ws + W3_PACKED);
        int* gcur   = (int*)(ws + W3_GCUR);
        int* noff   = (int*)(ws + W3_NODEOFF);
        int* ncnt   = (int*)(ws + W3_NODECNT);
        unsigned int* w16u = (unsigned int*)(ws + W3_W16);

        hipMemsetAsync(gcur, 0, (size_t)NB * sizeof(int), stream);

        k_partition  <<<PBLK, 1024, 0, stream>>>(src, dst, gcur, packed);
        k_sortb_conv <<<NB + CONVB + 1, 512, 0, stream>>>(
            feat, Ws, Wn, ff16, w16u, gcur, packed, noff, ncnt);
        k_agg_f16    <<<AGG_BLOCKS, 256, 0, stream>>>(
            ff16, noff, ncnt, packed, out);
        k_update_mfma<<<(N_NODES + 63) / 64, 256, 0, stream>>>(
            ff16, (const _Float16*)w16u, out);
    } else {
        float* deg = (float*)ws;
        hipMemsetAsync(out, 0, (size_t)N_NODES * D * sizeof(float), stream);
        hipMemsetAsync(deg, 0, (size_t)N_NODES * sizeof(float), stream);
        sage_scatter<<<(N_EDGES * 64) / 256, 256, 0, stream>>>(feat, src, dst, out, deg);
        k_update_div<<<1024, 256, 0, stream>>>(feat, Ws, Wn, deg, out);
    }
}